// Round 8
// baseline (200.544 us; speedup 1.0000x reference)
//
#include <hip/hip_runtime.h>

// ShiftImgPreprocessor: out[b,t,c,i,j] = img[b,t,c, clamp(i+sy-4,0,95), clamp(j+sx-4,0,95)] / 255 - 0.5
//
// v7: straight-line 3-deep software-pipelined half-plane streaming.
// Matrix so far (kernel dispatch): v1 one-shot dual-load 58.6us; v2 unaligned
// 67.2; v3 8-load burst 66.8; v4 plain store ~59; v5 persistent (compiler
// COLLAPSED pipeline, VGPR=20) 70-73; v6 LDS-staged 1.0x reads 66.5.
// Load width / burst MLP / store policy / persistence / byte count: ALL null.
// Last discriminator: none of these sustained steady-state reads-in-flight.
// v7 reproduces the m13-copy shape without v5's collapse:
//  - block(128thr) owns ONE contiguous half-plane (48 rows = 18KB stream);
//    9 float4-stages per thread, FULLY UNROLLED straight-line with PRE(i+3)
//    issued between CON(i)s. Static register slots A[i],B[i] (all indices
//    compile-time -> registers, rule #20), so the compiler emits counted
//    vmcnt(N) waits and keeps 3 stages (6KB/wave) of reads in flight.
//  - per-stage math = v1's verified dual ALIGNED dwordx4 + wave-uniform
//    phase blend (dx&3, scalar branch) + verified uniform-dx edge table
//    (passed in v2/v3/v5 runs, absmax 2^-10 every time).
//  - XCD-chunked bijective block swizzle (6144%8==0): each XCD streams a
//    contiguous 27MB region through its own L2/EA port.
// Pre-commit: null result (58-67us again) => harness mixed-stream machine
// rate ~2.6 TB/s DRAM is the ceiling for this dispatch; declare and stop.

#define PAD 4
#define NB  256
#define TT  4
#define CC  3
#define HH  96
#define WW  96
#define W4  (WW / 4)              // 24 float4 per row
#define TC  (TT * CC)             // 12 planes per batch
#define HW  (HH * WW)             // 9216 floats per plane
#define BLOCK 128
#define NHP (NB * TC * 2)         // 6144 half-planes
#define STAGES 9                  // (HW/2) / 4 / BLOCK = 1152/128

typedef float vfloat4 __attribute__((ext_vector_type(4)));

__global__ __launch_bounds__(BLOCK) void ShiftImgPreprocessor_36679020708143_kernel(
    const float* __restrict__ img,
    const int*   __restrict__ shift,
    float*       __restrict__ out)
{
    const int bid = blockIdx.x;
    // XCD-chunked bijective swizzle: XCD x gets half-planes [x*768, (x+1)*768)
    const int hp = (bid & 7) * (NHP / 8) + (bid >> 3);
    const int pl = hp >> 1;              // plane id = b*TC + tc (uniform)
    const int h  = hp & 1;               // half: rows [h*48, h*48+48)
    const int b  = pl / TC;
    const int t  = threadIdx.x;

    // block-uniform -> scalar
    const int dx = shift[2 * b + 0] - PAD;   // [-4, 4]
    const int dy = shift[2 * b + 1] - PAD;

    const float* __restrict__ src = img + (size_t)pl * HW;
    float*       __restrict__ dst = out + (size_t)pl * HW;

    vfloat4 A[STAGES], B[STAGES];   // statically indexed -> registers

    // issue stage i's two ALIGNED dwordx4 (consumed 3 stages later)
    #define PRE(i) { \
        const int u  = (i) * BLOCK + t;               /* [0,1152) */ \
        const int k  = h * 48 + u / W4;               /* output row */ \
        const int c  = u % W4;                        /* float4 col */ \
        const int yy = min(max(k + dy, 0), HH - 1); \
        const vfloat4* __restrict__ sv = (const vfloat4*)(src + yy * WW); \
        const int s  = 4 * c + dx;                    /* [-4, 96] */ \
        const int a4 = s >> 2; \
        const int a0 = min(max(a4, 0), W4 - 1); \
        const int a1 = min(a4 + 1, W4 - 1); \
        A[i] = sv[a0]; \
        B[i] = sv[a1]; }

    // blend + edge-fix + scale + store for stage i
    #define CON(i) { \
        const int u = (i) * BLOCK + t; \
        const int k = h * 48 + u / W4; \
        const int c = u % W4; \
        const int s = 4 * c + dx; \
        const vfloat4 Av = A[i], Bv = B[i]; \
        vfloat4 o; \
        switch (dx & 3) {                              /* uniform phase */ \
            case 0:  o = Av; break; \
            case 1:  o = (vfloat4){Av.y, Av.z, Av.w, Bv.x}; break; \
            case 2:  o = (vfloat4){Av.z, Av.w, Bv.x, Bv.y}; break; \
            default: o = (vfloat4){Av.w, Bv.x, Bv.y, Bv.z}; break; } \
        if (s < 0 || s > WW - 4) {                     /* edge replicate */ \
            switch (dx) {                              /* uniform */ \
                case -4: \
                case -3: o = (vfloat4){Av.x, Av.x, Av.x, Av.x}; break; \
                case -2: o = (vfloat4){Av.x, Av.x, Av.x, Av.y}; break; \
                case -1: o = (vfloat4){Av.x, Av.x, Av.y, Av.z}; break; \
                case  1: o = (vfloat4){Av.y, Av.z, Av.w, Av.w}; break; \
                case  2: o = (vfloat4){Av.z, Av.w, Av.w, Av.w}; break; \
                default: o = (vfloat4){Av.w, Av.w, Av.w, Av.w}; break; } } \
        o = o * (1.0f / 255.0f) - 0.5f; \
        *(vfloat4*)(dst + (size_t)k * WW + 4 * c) = o; }

    // 3-deep straight-line pipeline over 9 stages
    PRE(0) PRE(1) PRE(2)
    CON(0) PRE(3)
    CON(1) PRE(4)
    CON(2) PRE(5)
    CON(3) PRE(6)
    CON(4) PRE(7)
    CON(5) PRE(8)
    CON(6) CON(7) CON(8)

    #undef PRE
    #undef CON
}

extern "C" void kernel_launch(void* const* d_in, const int* in_sizes, int n_in,
                              void* d_out, int out_size, void* d_ws, size_t ws_size,
                              hipStream_t stream) {
    const float* img   = (const float*)d_in[0];
    const int*   shift = (const int*)d_in[1];
    float*       out   = (float*)d_out;

    ShiftImgPreprocessor_36679020708143_kernel<<<dim3(NHP), BLOCK, 0, stream>>>(img, shift, out);
}

// Round 9
// 190.469 us; speedup vs baseline: 1.0529x; 1.0529x over previous
//
#include <hip/hip_runtime.h>

// ShiftImgPreprocessor: out[b,t,c,i,j] = img[b,t,c, clamp(i+sy-4,0,95), clamp(j+sx-4,0,95)] / 255 - 0.5
//
// v8 = RESTORE v1 (session best: 193.0us total, kernel ~58.6us). TERMINAL.
//
// Session evidence (kernel dispatch times):
//   v1 58.6 | v2 unaligned 67.2 | v3 8-load burst 66.8 | v4 plain-store ~59
//   v5 persistent+prefetch 70-73 (compiler collapsed, VGPR=20)
//   v6 LDS-staged 1.0x reads 66.5 | v7 static 3-deep pipeline 69-71 (collapsed)
// Six orthogonal structural levers all null/negative; best = this baseline.
// Counters at best: DRAM 2.5-2.9/6.3 TB/s, VALUBusy 6-15%, occ 55-65%,
// 0 bank conflicts, vmem issue ~0.01 instr/cyc/CU, in-flight bytes 9x the
// Little's-law latency-hiding requirement. No visible pipe is saturated; the
// residual 2.4x gap to the 165MB-DRAM/6.8TB/s=24us floor sits below PMC
// visibility (TA/TCP/EA throttle or harness poison-fill cache-state) and did
// not respond to any kernel structure. Bench floor = ~135us harness fills +
// ~58us kernel = ~193us, which this kernel achieves.

#define PAD 4
#define NB  256   // batch
#define TT  4
#define CC  3
#define HH  96
#define WW  96
#define W4  (WW / 4)                    // 24 float4 per row
#define ROWS_PER_B (TT * CC * HH)       // 1152
#define V4_PER_B (ROWS_PER_B * W4)      // 27648 float4 per batch
#define BLOCK 256

typedef float vfloat4 __attribute__((ext_vector_type(4)));

__global__ __launch_bounds__(BLOCK) void ShiftImgPreprocessor_36679020708143_kernel(
    const float* __restrict__ img,
    const int*   __restrict__ shift,
    float*       __restrict__ out)
{
    const int b = blockIdx.y;
    const int v = blockIdx.x * BLOCK + threadIdx.x;   // [0, V4_PER_B)

    const int j4 = v % W4;           // which float4 in the row
    const int r_ = v / W4;           // row index within batch: [0, T*C*H)
    const int i  = r_ % HH;          // output row
    const int tc = r_ / HH;          // fused (t,c) plane index

    // block-uniform -> SGPR loads
    const int dx = shift[2 * b + 0] - PAD;   // in [-4, 4]
    const int dy = shift[2 * b + 1] - PAD;

    const int yy = min(max(i + dy, 0), HH - 1);

    const size_t plane = ((size_t)b * (TT * CC) + tc) * (size_t)(HH * WW);
    const float* __restrict__ srcrow = img + plane + (size_t)yy * WW;

    const int j = j4 * 4;
    const float k = 1.0f / 255.0f;
    vfloat4 o;

    if (j4 == 0 || j4 == W4 - 1) {
        // edge float4: may need horizontal clamping -> scalar clamped gather
        const int x0 = min(max(j + 0 + dx, 0), WW - 1);
        const int x1 = min(max(j + 1 + dx, 0), WW - 1);
        const int x2 = min(max(j + 2 + dx, 0), WW - 1);
        const int x3 = min(max(j + 3 + dx, 0), WW - 1);
        o = (vfloat4){srcrow[x0], srcrow[x1], srcrow[x2], srcrow[x3]};
    } else {
        // interior: s = j+dx in [0,92]; source floats s..s+3 live in vecs a4, a4+1
        const int s  = j + dx;
        const int a4 = s >> 2;                 // consecutive lanes -> consecutive vecs
        const int r  = dx & 3;                 // SGPR-uniform phase -> scalar branch
        const vfloat4* __restrict__ sv = (const vfloat4*)srcrow;
        const vfloat4 V0 = sv[a4];
        const vfloat4 V1 = sv[min(a4 + 1, W4 - 1)];   // unused when r==0; clamp avoids OOB
        switch (r) {
            case 0:  o = V0; break;
            case 1:  o = (vfloat4){V0.y, V0.z, V0.w, V1.x}; break;
            case 2:  o = (vfloat4){V0.z, V0.w, V1.x, V1.y}; break;
            default: o = (vfloat4){V0.w, V1.x, V1.y, V1.z}; break;
        }
    }

    o = o * k - 0.5f;

    vfloat4* outv = (vfloat4*)(out + plane + (size_t)i * WW + j);
    __builtin_nontemporal_store(o, outv);
}

extern "C" void kernel_launch(void* const* d_in, const int* in_sizes, int n_in,
                              void* d_out, int out_size, void* d_ws, size_t ws_size,
                              hipStream_t stream) {
    const float* img   = (const float*)d_in[0];
    const int*   shift = (const int*)d_in[1];
    float*       out   = (float*)d_out;

    dim3 grid(V4_PER_B / BLOCK, NB);   // (108, 256)
    ShiftImgPreprocessor_36679020708143_kernel<<<grid, BLOCK, 0, stream>>>(img, shift, out);
}